// Round 1
// baseline (490.365 us; speedup 1.0000x reference)
//
#include <hip/hip_runtime.h>
#include <math.h>

#define NN 8192
#define GG 32
#define SS 256
#define TILE 64

// bh[i,j] = exp((sim[i,j] - m[i,gJ])/tau) / l[i,gJ]
// out[i,j] = bh[i,j]*bh[j,i] = exp((sim[i,j]+sim[j,i])/tau - c[i,gJ] - c[j,gI])
// with c[i,g] = m[i,g]/tau + ln(l[i,g]).

// Pass 1: one wave per (row, group). 256 floats/wave via float4, shuffle-reduce.
__global__ __launch_bounds__(256) void bh_stats(const float* __restrict__ sim,
                                                float* __restrict__ cst) {
    const int wave = threadIdx.x >> 6;
    const int lane = threadIdx.x & 63;
    const int flat = blockIdx.x * 4 + wave;   // flat = row*GG + g
    const int row  = flat >> 5;               // /GG
    const int g    = flat & (GG - 1);
    const int jbase = g * SS + lane * 4;

    const float4 v = *(const float4*)(sim + (size_t)row * NN + jbase);
    const float x0 = (jbase + 0 == row) ? -INFINITY : v.x;
    const float x1 = (jbase + 1 == row) ? -INFINITY : v.y;
    const float x2 = (jbase + 2 == row) ? -INFINITY : v.z;
    const float x3 = (jbase + 3 == row) ? -INFINITY : v.w;

    float m = fmaxf(fmaxf(x0, x1), fmaxf(x2, x3));
#pragma unroll
    for (int off = 32; off >= 1; off >>= 1)
        m = fmaxf(m, __shfl_xor(m, off, 64));

    const float invt = 10.0f;  // 1/TAU
    float s = __expf((x0 - m) * invt) + __expf((x1 - m) * invt)
            + __expf((x2 - m) * invt) + __expf((x3 - m) * invt);
#pragma unroll
    for (int off = 32; off >= 1; off >>= 1)
        s += __shfl_xor(s, off, 64);

    if (lane == 0)
        cst[flat] = m * invt + __logf(s);
}

// Pass 2: tile-pair (bi,bj), bi<=bj. Each 256-thread block loads tile A=(I,J)
// and tile B=(J,I) (float4 coalesced, also staged to LDS for the transposed
// operand), then writes both output tiles. Each element of sim is read from
// HBM exactly once in this pass.
__global__ __launch_bounds__(256) void bh_combine(const float* __restrict__ sim,
                                                  const float* __restrict__ cst,
                                                  float* __restrict__ out) {
    const int bi = blockIdx.y, bj = blockIdx.x;
    if (bj < bi) return;

    __shared__ float As[TILE][TILE + 1];
    __shared__ float Bs[TILE][TILE + 1];
    __shared__ float cA[TILE], cB[TILE];

    const int I = bi * TILE, J = bj * TILE;
    const int gI = I / SS, gJ = J / SS;
    const int t = threadIdx.x;

    if (t < TILE)            cA[t]        = cst[(I + t) * GG + gJ];
    else if (t < 2 * TILE)   cB[t - TILE] = cst[(J + (t - TILE)) * GG + gI];

    float4 a[4], b[4];
    int rr[4], cc[4];
#pragma unroll
    for (int k = 0; k < 4; ++k) {
        const int q = t + 256 * k;
        const int r = q >> 4;          // row within tile
        const int c = (q & 15) << 2;   // col within tile (float4)
        rr[k] = r; cc[k] = c;
        a[k] = *(const float4*)(sim + (size_t)(I + r) * NN + J + c);
        b[k] = *(const float4*)(sim + (size_t)(J + r) * NN + I + c);
        As[r][c + 0] = a[k].x; As[r][c + 1] = a[k].y;
        As[r][c + 2] = a[k].z; As[r][c + 3] = a[k].w;
        Bs[r][c + 0] = b[k].x; Bs[r][c + 1] = b[k].y;
        Bs[r][c + 2] = b[k].z; Bs[r][c + 3] = b[k].w;
    }
    __syncthreads();

    const float invt = 10.0f;  // 1/TAU
#pragma unroll
    for (int k = 0; k < 4; ++k) {
        const int r = rr[k], c = cc[k];
        const float ca = cA[r];
        float4 o;
        o.x = (I + r == J + c + 0) ? 0.0f
            : __expf((a[k].x + Bs[c + 0][r]) * invt - ca - cB[c + 0]);
        o.y = (I + r == J + c + 1) ? 0.0f
            : __expf((a[k].y + Bs[c + 1][r]) * invt - ca - cB[c + 1]);
        o.z = (I + r == J + c + 2) ? 0.0f
            : __expf((a[k].z + Bs[c + 2][r]) * invt - ca - cB[c + 2]);
        o.w = (I + r == J + c + 3) ? 0.0f
            : __expf((a[k].w + Bs[c + 3][r]) * invt - ca - cB[c + 3]);
        *(float4*)(out + (size_t)(I + r) * NN + J + c) = o;

        if (bi != bj) {
            const float cb = cB[r];
            float4 p;
            p.x = __expf((b[k].x + As[c + 0][r]) * invt - cb - cA[c + 0]);
            p.y = __expf((b[k].y + As[c + 1][r]) * invt - cb - cA[c + 1]);
            p.z = __expf((b[k].z + As[c + 2][r]) * invt - cb - cA[c + 2]);
            p.w = __expf((b[k].w + As[c + 3][r]) * invt - cb - cA[c + 3]);
            *(float4*)(out + (size_t)(J + r) * NN + I + c) = p;
        }
    }
}

extern "C" void kernel_launch(void* const* d_in, const int* in_sizes, int n_in,
                              void* d_out, int out_size, void* d_ws, size_t ws_size,
                              hipStream_t stream) {
    const float* sim = (const float*)d_in[0];
    float* out = (float*)d_out;
    float* cst = (float*)d_ws;  // NN*GG floats = 1 MB of scratch

    // Pass 1: 8192*32 wave-tasks, 4 waves (256 thr) per block.
    bh_stats<<<dim3(NN * GG / 4), dim3(256), 0, stream>>>(sim, cst);
    // Pass 2: 128x128 tile grid, lower-triangle blocks exit immediately.
    bh_combine<<<dim3(NN / TILE, NN / TILE), dim3(256), 0, stream>>>(sim, cst, out);
}

// Round 2
// 460.287 us; speedup vs baseline: 1.0653x; 1.0653x over previous
//
#include <hip/hip_runtime.h>
#include <math.h>

#define NN 8192
#define GG 32
#define SS 256
#define TILE 64

typedef float v4f __attribute__((ext_vector_type(4)));

// bh[i,j] = exp((sim[i,j] - m[i,gJ])/tau) / l[i,gJ]
// out[i,j] = bh[i,j]*bh[j,i] = exp((sim[i,j]+sim[j,i])/tau - c[i,gJ] - c[j,gI])
// with c[i,g] = m[i,g]/tau + ln(l[i,g]).

// Pass 1: one wave per (row, group). 256 floats/wave via float4, shuffle-reduce.
// Side effect: streams all 256 MB of sim through L3, leaving it resident.
__global__ __launch_bounds__(256) void bh_stats(const float* __restrict__ sim,
                                                float* __restrict__ cst) {
    const int wave = threadIdx.x >> 6;
    const int lane = threadIdx.x & 63;
    const int flat = blockIdx.x * 4 + wave;   // flat = row*GG + g
    const int row  = flat >> 5;               // /GG
    const int g    = flat & (GG - 1);
    const int jbase = g * SS + lane * 4;

    const float4 v = *(const float4*)(sim + (size_t)row * NN + jbase);
    const float x0 = (jbase + 0 == row) ? -INFINITY : v.x;
    const float x1 = (jbase + 1 == row) ? -INFINITY : v.y;
    const float x2 = (jbase + 2 == row) ? -INFINITY : v.z;
    const float x3 = (jbase + 3 == row) ? -INFINITY : v.w;

    float m = fmaxf(fmaxf(x0, x1), fmaxf(x2, x3));
#pragma unroll
    for (int off = 32; off >= 1; off >>= 1)
        m = fmaxf(m, __shfl_xor(m, off, 64));

    const float invt = 10.0f;  // 1/TAU
    float s = __expf((x0 - m) * invt) + __expf((x1 - m) * invt)
            + __expf((x2 - m) * invt) + __expf((x3 - m) * invt);
#pragma unroll
    for (int off = 32; off >= 1; off >>= 1)
        s += __shfl_xor(s, off, 64);

    if (lane == 0)
        cst[flat] = m * invt + __logf(s);
}

// Pass 2: triangular grid of tile-pairs (bi,bj), bi<=bj. Each 256-thread block
// loads tile A=(I,J) and tile B=(J,I) (float4 coalesced; staged to LDS for the
// transposed operand) and writes both output tiles with NONTEMPORAL stores so
// the 256 MB output stream does not evict sim from the 256 MB L3.
__global__ __launch_bounds__(256) void bh_combine(const float* __restrict__ sim,
                                                  const float* __restrict__ cst,
                                                  float* __restrict__ out) {
    // Decode triangular index: M=128 tiles/dim, start(i) = i*(257-i)/2.
    const int M = NN / TILE;
    const int f = blockIdx.x;
    int bi = (int)floorf((257.0f - sqrtf((float)(66049 - 8 * f))) * 0.5f);
    while (bi * (2 * M + 1 - bi) / 2 > f) --bi;
    while ((bi + 1) * (2 * M + 1 - (bi + 1)) / 2 <= f) ++bi;
    const int bj = bi + (f - bi * (2 * M + 1 - bi) / 2);

    __shared__ float As[TILE][TILE + 1];
    __shared__ float Bs[TILE][TILE + 1];
    __shared__ float cA[TILE], cB[TILE];

    const int I = bi * TILE, J = bj * TILE;
    const int gI = I / SS, gJ = J / SS;
    const int t = threadIdx.x;

    if (t < TILE)            cA[t]        = cst[(I + t) * GG + gJ];
    else if (t < 2 * TILE)   cB[t - TILE] = cst[(J + (t - TILE)) * GG + gI];

    float4 a[4], b[4];
    int rr[4], cc[4];
#pragma unroll
    for (int k = 0; k < 4; ++k) {
        const int q = t + 256 * k;
        const int r = q >> 4;          // row within tile
        const int c = (q & 15) << 2;   // col within tile (float4)
        rr[k] = r; cc[k] = c;
        a[k] = *(const float4*)(sim + (size_t)(I + r) * NN + J + c);
        b[k] = *(const float4*)(sim + (size_t)(J + r) * NN + I + c);
        As[r][c + 0] = a[k].x; As[r][c + 1] = a[k].y;
        As[r][c + 2] = a[k].z; As[r][c + 3] = a[k].w;
        Bs[r][c + 0] = b[k].x; Bs[r][c + 1] = b[k].y;
        Bs[r][c + 2] = b[k].z; Bs[r][c + 3] = b[k].w;
    }
    __syncthreads();

    const float invt = 10.0f;  // 1/TAU
#pragma unroll
    for (int k = 0; k < 4; ++k) {
        const int r = rr[k], c = cc[k];
        const float ca = cA[r];
        v4f o;
        o.x = (I + r == J + c + 0) ? 0.0f
            : __expf((a[k].x + Bs[c + 0][r]) * invt - ca - cB[c + 0]);
        o.y = (I + r == J + c + 1) ? 0.0f
            : __expf((a[k].y + Bs[c + 1][r]) * invt - ca - cB[c + 1]);
        o.z = (I + r == J + c + 2) ? 0.0f
            : __expf((a[k].z + Bs[c + 2][r]) * invt - ca - cB[c + 2]);
        o.w = (I + r == J + c + 3) ? 0.0f
            : __expf((a[k].w + Bs[c + 3][r]) * invt - ca - cB[c + 3]);
        __builtin_nontemporal_store(o, (v4f*)(out + (size_t)(I + r) * NN + J + c));

        if (bi != bj) {
            const float cb = cB[r];
            v4f p;
            p.x = __expf((b[k].x + As[c + 0][r]) * invt - cb - cA[c + 0]);
            p.y = __expf((b[k].y + As[c + 1][r]) * invt - cb - cA[c + 1]);
            p.z = __expf((b[k].z + As[c + 2][r]) * invt - cb - cA[c + 2]);
            p.w = __expf((b[k].w + As[c + 3][r]) * invt - cb - cA[c + 3]);
            __builtin_nontemporal_store(p, (v4f*)(out + (size_t)(J + r) * NN + I + c));
        }
    }
}

extern "C" void kernel_launch(void* const* d_in, const int* in_sizes, int n_in,
                              void* d_out, int out_size, void* d_ws, size_t ws_size,
                              hipStream_t stream) {
    const float* sim = (const float*)d_in[0];
    float* out = (float*)d_out;
    float* cst = (float*)d_ws;  // NN*GG floats = 1 MB of scratch

    // Pass 1: 8192*32 wave-tasks, 4 waves (256 thr) per block.
    bh_stats<<<dim3(NN * GG / 4), dim3(256), 0, stream>>>(sim, cst);
    // Pass 2: triangular tile grid, M*(M+1)/2 = 8256 blocks.
    const int M = NN / TILE;
    bh_combine<<<dim3(M * (M + 1) / 2), dim3(256), 0, stream>>>(sim, cst, out);
}